// Round 1
// baseline (121.503 us; speedup 1.0000x reference)
//
#include <hip/hip_runtime.h>

// CenterLoss: loss = (sum_b clip(||y_b - centers[label_b]||^2, 1e-12, 1e12)
//                     + B*(C-1)*1e-12) / B * loss_weight
// The reference's [B,C] distmat is masked to one entry per row, so we only
// need a gather + per-row squared distance. Memory-bound (~17 MB total).

__global__ __launch_bounds__(256) void center_loss_main(
    const float4* __restrict__ y,        // [B, 32] float4  (=128 f32)
    const int*    __restrict__ labels,   // [B]
    const float4* __restrict__ centers,  // [C, 32] float4
    float*        __restrict__ partial,  // [1] accumulator (pre-zeroed)
    int batch) {
  __shared__ float wave_sums[4];         // 256 threads = 4 waves
  const int tid    = blockIdx.x * blockDim.x + threadIdx.x;
  const int lane32 = threadIdx.x & 31;   // lane within half-wave
  const int half   = tid >> 5;           // global half-wave id = row id
  const int nhalf  = (gridDim.x * blockDim.x) >> 5;

  float acc = 0.f;
  for (int row = half; row < batch; row += nhalf) {
    const int lbl = labels[row];
    const float4 a = y[(size_t)row * 32 + lane32];
    const float4 c = centers[(size_t)lbl * 32 + lane32];
    const float dx = a.x - c.x;
    const float dy = a.y - c.y;
    const float dz = a.z - c.z;
    const float dw = a.w - c.w;
    float d = dx * dx + dy * dy + dz * dz + dw * dw;
    // butterfly reduce within the 32-lane half-wave (masks < 32 stay in-group)
    #pragma unroll
    for (int off = 16; off >= 1; off >>= 1) d += __shfl_xor(d, off);
    if (lane32 == 0) acc += fminf(fmaxf(d, 1e-12f), 1e12f);
  }

  // full-wave reduce (only lanes 0 and 32 hold nonzero acc)
  #pragma unroll
  for (int off = 32; off >= 1; off >>= 1) acc += __shfl_xor(acc, off);

  const int wave = threadIdx.x >> 6;
  if ((threadIdx.x & 63) == 0) wave_sums[wave] = acc;
  __syncthreads();
  if (threadIdx.x == 0) {
    const float s = wave_sums[0] + wave_sums[1] + wave_sums[2] + wave_sums[3];
    atomicAdd(partial, s);  // device-scope by default on CDNA
  }
}

__global__ void center_loss_finalize(const float* __restrict__ partial,
                                     const float* __restrict__ lw,
                                     float*       __restrict__ out,
                                     int batch, int num_classes) {
  // masked-out entries (zero) are clipped up to 1e-12 and summed by the ref
  const float pad =
      (float)((double)batch * (double)(num_classes - 1) * 1e-12);
  out[0] = (partial[0] + pad) / (float)batch * lw[0];
}

extern "C" void kernel_launch(void* const* d_in, const int* in_sizes, int n_in,
                              void* d_out, int out_size, void* d_ws, size_t ws_size,
                              hipStream_t stream) {
  const float* y       = (const float*)d_in[0];
  const int*   labels  = (const int*)d_in[1];   // harness delivers ints as i32
  const float* centers = (const float*)d_in[2];
  const float* lw      = (const float*)d_in[3];

  const int batch       = in_sizes[0] / 128;    // FEAT_DIM = 128
  const int num_classes = in_sizes[2] / 128;

  float* partial = (float*)d_ws;
  hipMemsetAsync(partial, 0, sizeof(float), stream);

  // 1 row per half-wave, 8 rows per 256-thread block
  const int blocks = (batch + 7) / 8;           // 4096 for B=32768
  center_loss_main<<<blocks, 256, 0, stream>>>(
      (const float4*)y, labels, (const float4*)centers, partial, batch);
  center_loss_finalize<<<1, 1, 0, stream>>>(partial, lw, (float*)d_out,
                                            batch, num_classes);
}

// Round 2
// 71.823 us; speedup vs baseline: 1.6917x; 1.6917x over previous
//
#include <hip/hip_runtime.h>

// CenterLoss: loss = (sum_b clip(||y_b - centers[label_b]||^2, 1e-12, 1e12)
//                     + B*(C-1)*1e-12) / B * loss_weight
// R1: removed single-address atomicAdd (was serializing 4096 atomics at one
// TCC ~ 56us), removed memset launch, deferred the cross-lane reduce to once
// per thread (per-row clip is a no-op: dist ~ 2*D = 256 >> 1e-12), and gave
// each half-wave 4 independent rows for memory-level parallelism.

__global__ __launch_bounds__(256) void center_loss_main(
    const float4* __restrict__ y,        // [B, 32] float4  (=128 f32)
    const int*    __restrict__ labels,   // [B]
    const float4* __restrict__ centers,  // [C, 32] float4
    float*        __restrict__ partial,  // [gridDim.x] per-block sums
    int batch) {
  __shared__ float wave_sums[4];         // 256 threads = 4 waves
  const int lane32 = threadIdx.x & 31;   // lane within half-wave
  const int hw     = threadIdx.x >> 5;   // half-wave id in block, 0..7
  const int row0   = blockIdx.x * 32 + hw * 4;

  float acc = 0.f;
  #pragma unroll
  for (int r = 0; r < 4; ++r) {
    const int row = row0 + r;
    if (row < batch) {
      const int    lbl = labels[row];
      const float4 a   = y[(size_t)row * 32 + lane32];
      const float4 c   = centers[(size_t)lbl * 32 + lane32];
      const float dx = a.x - c.x;
      const float dy = a.y - c.y;
      const float dz = a.z - c.z;
      const float dw = a.w - c.w;
      acc += dx * dx + dy * dy + dz * dz + dw * dw;
    }
  }

  // one full-wave butterfly reduce per thread (not per row)
  #pragma unroll
  for (int off = 32; off >= 1; off >>= 1) acc += __shfl_xor(acc, off);

  if ((threadIdx.x & 63) == 0) wave_sums[threadIdx.x >> 6] = acc;
  __syncthreads();
  if (threadIdx.x == 0) {
    partial[blockIdx.x] =
        wave_sums[0] + wave_sums[1] + wave_sums[2] + wave_sums[3];
  }
}

__global__ __launch_bounds__(256) void center_loss_finalize(
    const float* __restrict__ partial, int nparts,
    const float* __restrict__ lw,
    float*       __restrict__ out,
    int batch, int num_classes) {
  __shared__ float wave_sums[4];
  float acc = 0.f;
  for (int i = threadIdx.x; i < nparts; i += 256) acc += partial[i];
  #pragma unroll
  for (int off = 32; off >= 1; off >>= 1) acc += __shfl_xor(acc, off);
  if ((threadIdx.x & 63) == 0) wave_sums[threadIdx.x >> 6] = acc;
  __syncthreads();
  if (threadIdx.x == 0) {
    const float total =
        wave_sums[0] + wave_sums[1] + wave_sums[2] + wave_sums[3];
    // masked-out entries (zero) get clipped up to 1e-12 and summed by the ref
    const float pad =
        (float)((double)batch * (double)(num_classes - 1) * 1e-12);
    out[0] = (total + pad) / (float)batch * lw[0];
  }
}

extern "C" void kernel_launch(void* const* d_in, const int* in_sizes, int n_in,
                              void* d_out, int out_size, void* d_ws, size_t ws_size,
                              hipStream_t stream) {
  const float* y       = (const float*)d_in[0];
  const int*   labels  = (const int*)d_in[1];   // harness delivers ints as i32
  const float* centers = (const float*)d_in[2];
  const float* lw      = (const float*)d_in[3];

  const int batch       = in_sizes[0] / 128;    // FEAT_DIM = 128
  const int num_classes = in_sizes[2] / 128;

  float* partial = (float*)d_ws;

  // 32 rows per block (4 rows per 32-lane half-wave), B=32768 -> 1024 blocks
  const int blocks = (batch + 31) / 32;
  center_loss_main<<<blocks, 256, 0, stream>>>(
      (const float4*)y, labels, (const float4*)centers, partial, batch);
  center_loss_finalize<<<1, 256, 0, stream>>>(partial, blocks, lw,
                                              (float*)d_out, batch,
                                              num_classes);
}

// Round 3
// 69.834 us; speedup vs baseline: 1.7399x; 1.0285x over previous
//
#include <hip/hip_runtime.h>

// CenterLoss: loss = (sum_b clip(||y_b - centers[label_b]||^2, 1e-12, 1e12)
//                     + B*(C-1)*1e-12) / B * loss_weight
// R2: dur_us is dominated by harness restore/poison (~62-65us of 256MiB ws
// fills + d_in restore, visible as fillBufferAligned in rocprof). Our share
// is ~7-10us. This round: int4-batched label loads (1 round trip not 4 on
// the gather critical path), 1024-thread finalize (1 load/thread), max MLP.

__global__ __launch_bounds__(256) void center_loss_main(
    const float4* __restrict__ y,        // [B, 32] float4  (=128 f32)
    const int4*   __restrict__ labels4,  // [B/4]
    const float4* __restrict__ centers,  // [C, 32] float4
    float*        __restrict__ partial,  // [gridDim.x] per-block sums
    int batch) {
  __shared__ float wave_sums[4];         // 256 threads = 4 waves
  const int lane32 = threadIdx.x & 31;   // lane within half-wave
  const int hw     = threadIdx.x >> 5;   // half-wave id in block, 0..7
  const int row0   = blockIdx.x * 32 + hw * 4;

  float acc = 0.f;
  if (row0 + 3 < batch) {
    // one broadcast int4 load fetches all 4 labels for this half-wave
    const int4 lbl = labels4[row0 >> 2];
    const float4* yp = y + (size_t)row0 * 32 + lane32;
    // issue all 8 independent 16B loads up front (MLP)
    const float4 a0 = yp[0];
    const float4 a1 = yp[32];
    const float4 a2 = yp[64];
    const float4 a3 = yp[96];
    const float4 c0 = centers[(size_t)lbl.x * 32 + lane32];
    const float4 c1 = centers[(size_t)lbl.y * 32 + lane32];
    const float4 c2 = centers[(size_t)lbl.z * 32 + lane32];
    const float4 c3 = centers[(size_t)lbl.w * 32 + lane32];
    float d0 = (a0.x - c0.x) * (a0.x - c0.x) + (a0.y - c0.y) * (a0.y - c0.y) +
               (a0.z - c0.z) * (a0.z - c0.z) + (a0.w - c0.w) * (a0.w - c0.w);
    float d1 = (a1.x - c1.x) * (a1.x - c1.x) + (a1.y - c1.y) * (a1.y - c1.y) +
               (a1.z - c1.z) * (a1.z - c1.z) + (a1.w - c1.w) * (a1.w - c1.w);
    float d2 = (a2.x - c2.x) * (a2.x - c2.x) + (a2.y - c2.y) * (a2.y - c2.y) +
               (a2.z - c2.z) * (a2.z - c2.z) + (a2.w - c2.w) * (a2.w - c2.w);
    float d3 = (a3.x - c3.x) * (a3.x - c3.x) + (a3.y - c3.y) * (a3.y - c3.y) +
               (a3.z - c3.z) * (a3.z - c3.z) + (a3.w - c3.w) * (a3.w - c3.w);
    acc = (d0 + d1) + (d2 + d3);
  } else {
    // generic tail path (unused for B=32768)
    for (int r = 0; r < 4; ++r) {
      const int row = row0 + r;
      if (row < batch) {
        const int lbl = ((const int*)labels4)[row];
        const float4 a = y[(size_t)row * 32 + lane32];
        const float4 c = centers[(size_t)lbl * 32 + lane32];
        const float dx = a.x - c.x, dy = a.y - c.y;
        const float dz = a.z - c.z, dw = a.w - c.w;
        acc += dx * dx + dy * dy + dz * dz + dw * dw;
      }
    }
  }

  // one full-wave butterfly reduce per thread
  #pragma unroll
  for (int off = 32; off >= 1; off >>= 1) acc += __shfl_xor(acc, off);

  if ((threadIdx.x & 63) == 0) wave_sums[threadIdx.x >> 6] = acc;
  __syncthreads();
  if (threadIdx.x == 0) {
    partial[blockIdx.x] =
        wave_sums[0] + wave_sums[1] + wave_sums[2] + wave_sums[3];
  }
}

__global__ __launch_bounds__(1024) void center_loss_finalize(
    const float* __restrict__ partial, int nparts,
    const float* __restrict__ lw,
    float*       __restrict__ out,
    int batch, int num_classes) {
  __shared__ float wave_sums[16];        // 1024 threads = 16 waves
  float acc = (threadIdx.x < nparts) ? partial[threadIdx.x] : 0.f;
  for (int i = threadIdx.x + 1024; i < nparts; i += 1024) acc += partial[i];
  #pragma unroll
  for (int off = 32; off >= 1; off >>= 1) acc += __shfl_xor(acc, off);
  if ((threadIdx.x & 63) == 0) wave_sums[threadIdx.x >> 6] = acc;
  __syncthreads();
  if (threadIdx.x < 64) {
    float s = (threadIdx.x < 16) ? wave_sums[threadIdx.x] : 0.f;
    #pragma unroll
    for (int off = 8; off >= 1; off >>= 1) s += __shfl_xor(s, off);
    if (threadIdx.x == 0) {
      // masked-out entries (zero) get clipped to 1e-12 and summed by the ref
      const float pad =
          (float)((double)batch * (double)(num_classes - 1) * 1e-12);
      out[0] = (s + pad) / (float)batch * lw[0];
    }
  }
}

extern "C" void kernel_launch(void* const* d_in, const int* in_sizes, int n_in,
                              void* d_out, int out_size, void* d_ws, size_t ws_size,
                              hipStream_t stream) {
  const float* y       = (const float*)d_in[0];
  const int*   labels  = (const int*)d_in[1];   // harness delivers ints as i32
  const float* centers = (const float*)d_in[2];
  const float* lw      = (const float*)d_in[3];

  const int batch       = in_sizes[0] / 128;    // FEAT_DIM = 128
  const int num_classes = in_sizes[2] / 128;

  float* partial = (float*)d_ws;

  // 32 rows per block (4 rows per 32-lane half-wave), B=32768 -> 1024 blocks
  const int blocks = (batch + 31) / 32;
  center_loss_main<<<blocks, 256, 0, stream>>>(
      (const float4*)y, (const int4*)labels, (const float4*)centers, partial,
      batch);
  center_loss_finalize<<<1, 1024, 0, stream>>>(partial, blocks, lw,
                                               (float*)d_out, batch,
                                               num_classes);
}